// Round 8
// baseline (194.531 us; speedup 1.0000x reference)
//
#include <hip/hip_runtime.h>
#include <hip/hip_bf16.h>
#include <cstdint>
#include <cstddef>
#include <cmath>

#define B_  2
#define T_  2048
#define C_  1024
#define NH_ 16
#define HD_ 64

typedef __bf16 bf16;
typedef bf16  bf16x8 __attribute__((ext_vector_type(8)));
typedef bf16  bf16x4 __attribute__((ext_vector_type(4)));
typedef float f32x4  __attribute__((ext_vector_type(4)));

#define MFMA16(a, b, c) __builtin_amdgcn_mfma_f32_16x16x32_bf16((a), (b), (c), 0, 0, 0)

// Async 16B global->LDS; LDS dest = wave-uniform base + lane*16.
__device__ __forceinline__ void gld_lds16(const bf16* g, bf16* lds_base_uniform) {
    __builtin_amdgcn_global_load_lds(
        (const __attribute__((address_space(1))) uint32_t*)g,
        (__attribute__((address_space(3))) uint32_t*)lds_base_uniform,
        16, 0, 0);
}

// ---------------------------------------------------------------------------
// Fused casts: blocks 0..4095 -> x (4 Mi elems); 4096..5119 -> all 4 weights.
// Wq is pre-scaled by 0.125*log2(e) so attention scores are exp2-ready.
// ---------------------------------------------------------------------------
__global__ __launch_bounds__(256) void cast_all(const float* __restrict__ x,
                                                const float* __restrict__ Wq,
                                                const float* __restrict__ Wk,
                                                const float* __restrict__ Wv,
                                                const float* __restrict__ Wo,
                                                bf16* __restrict__ xb,
                                                bf16* __restrict__ Wqk,
                                                bf16* __restrict__ Wvb,
                                                bf16* __restrict__ Wob) {
    const int bid = blockIdx.x;
    if (bid < 4096) {
        const int i = bid * 256 + threadIdx.x;
        float4 v = ((const float4*)x)[i];
        ((bf16x4*)xb)[i] = bf16x4{ (bf16)v.x, (bf16)v.y, (bf16)v.z, (bf16)v.w };
    } else {
        const float C1 = 0.1803368801111f;   // 0.125 * log2(e)
        const int i = (bid - 4096) * 256 + threadIdx.x;
        const int nw4 = C_ * C_ / 4;
        float4 q = ((const float4*)Wq)[i];
        float4 k = ((const float4*)Wk)[i];
        float4 v = ((const float4*)Wv)[i];
        float4 o = ((const float4*)Wo)[i];
        ((bf16x4*)Wqk)[i]       = bf16x4{ (bf16)(q.x * C1), (bf16)(q.y * C1),
                                          (bf16)(q.z * C1), (bf16)(q.w * C1) };
        ((bf16x4*)Wqk)[nw4 + i] = bf16x4{ (bf16)k.x, (bf16)k.y, (bf16)k.z, (bf16)k.w };
        ((bf16x4*)Wvb)[i]       = bf16x4{ (bf16)v.x, (bf16)v.y, (bf16)v.z, (bf16)v.w };
        ((bf16x4*)Wob)[i]       = bf16x4{ (bf16)o.x, (bf16)o.y, (bf16)o.z, (bf16)o.w };
    }
}

// ---------------------------------------------------------------------------
// 128x128 GEMM tile (NT), double-buffered LDS with raw s_barrier + vmcnt(4)
// so next-tile global_load_lds stays in flight across the barrier.
// As/Bs: 2 x 4096 bf16 each (32 KB total).
// ---------------------------------------------------------------------------
__device__ __forceinline__ void gemm_tile(bf16* As, bf16* Bs,
                                          const bf16* __restrict__ A,
                                          const bf16* __restrict__ W,
                                          bf16* __restrict__ Y,
                                          int N, int K, int m0, int n0) {
    const int tid  = threadIdx.x;
    const int lane = tid & 63;
    const int w    = tid >> 6;
    const int ml   = lane & 15;
    const int quad = lane >> 4;
    const int wm   = (w >> 1) * 64;
    const int wn   = (w & 1) * 64;
    const int sr   = lane >> 2;
    const int sc   = lane & 3;

    f32x4 acc[4][4] = {};

    auto stage = [&](int k0, int buf) {
#pragma unroll
        for (int ei = 0; ei < 2; ++ei) {
            const int e = w * 2 + ei;
            gld_lds16(A + (size_t)(m0 + e * 16 + sr) * K + k0 + sc * 8,
                      &As[buf * 4096 + e * 512]);
            gld_lds16(W + (size_t)(n0 + e * 16 + sr) * K + k0 + sc * 8,
                      &Bs[buf * 4096 + e * 512]);
        }
    };

    stage(0, 0);
    const int niter = K / 32;

    for (int it = 0; it < niter; ++it) {
        const int cur = it & 1;
        asm volatile("s_barrier" ::: "memory");   // prev iter's frag reads done
        if (it + 1 < niter) {
            stage((it + 1) * 32, cur ^ 1);
            asm volatile("s_waitcnt vmcnt(4)" ::: "memory");  // cur tile landed
        } else {
            asm volatile("s_waitcnt vmcnt(0)" ::: "memory");
        }
        asm volatile("s_barrier" ::: "memory");   // all waves' cur loads landed

        bf16x8 af[4], bfr[4];
#pragma unroll
        for (int t = 0; t < 4; ++t) {
            af[t]  = *(const bf16x8*)&As[cur * 4096 + (wm + t * 16 + ml) * 32 + quad * 8];
            bfr[t] = *(const bf16x8*)&Bs[cur * 4096 + (wn + t * 16 + ml) * 32 + quad * 8];
        }
#pragma unroll
        for (int mt = 0; mt < 4; ++mt)
#pragma unroll
            for (int nt = 0; nt < 4; ++nt)
                acc[mt][nt] = MFMA16(af[mt], bfr[nt], acc[mt][nt]);
    }

#pragma unroll
    for (int mt = 0; mt < 4; ++mt)
#pragma unroll
        for (int nt = 0; nt < 4; ++nt)
#pragma unroll
            for (int r = 0; r < 4; ++r) {
                const int row = m0 + wm + mt * 16 + quad * 4 + r;
                const int col = n0 + wn + nt * 16 + ml;
                Y[(size_t)row * N + col] = (bf16)acc[mt][nt][r];
            }
}

// Fused projections: blocks 0..511 -> QK = x @ Wqk^T   [4096 x 2048]
//                    blocks 512..767 -> V^T = Wv @ x^T [1024 x 4096]
__global__ __launch_bounds__(256) void proj_fused(const bf16* __restrict__ xb,
                                                  const bf16* __restrict__ Wqk,
                                                  const bf16* __restrict__ Wvb,
                                                  bf16* __restrict__ QKb,
                                                  bf16* __restrict__ VtT) {
    __shared__ __align__(16) bf16 As[2 * 4096];
    __shared__ __align__(16) bf16 Bs[2 * 4096];
    const int bid = blockIdx.x;
    if (bid < 512) {
        gemm_tile(As, Bs, xb, Wqk, QKb, 2048, 1024, (bid >> 4) * 128, (bid & 15) * 128);
    } else {
        const int b2 = bid - 512;
        gemm_tile(As, Bs, Wvb, xb, VtT, 4096, 1024, (b2 >> 5) * 128, (b2 & 31) * 128);
    }
}

// ---------------------------------------------------------------------------
// Output GEMM: out[4096,1024] = Ab @ Wo^T, fp32 out. 64x128 tile -> 512 blocks.
// Double-buffered staging (3 loads/thread/stage -> vmcnt(3)).
// ---------------------------------------------------------------------------
__global__ __launch_bounds__(256) void gemm_wo(const bf16* __restrict__ A,
                                               const bf16* __restrict__ W,
                                               float* __restrict__ Y) {
    __shared__ __align__(16) bf16 As[2 * 2048];
    __shared__ __align__(16) bf16 Bs[2 * 4096];
    const int tid  = threadIdx.x;
    const int lane = tid & 63;
    const int w    = tid >> 6;
    const int ml   = lane & 15;
    const int quad = lane >> 4;
    const int wm   = (w >> 1) * 32;
    const int wn   = (w & 1) * 64;
    const int m0   = blockIdx.y * 64;
    const int n0   = blockIdx.x * 128;
    const int sr   = lane >> 2;
    const int sc   = lane & 3;

    f32x4 acc[2][4] = {};

    auto stage = [&](int k0, int buf) {
        gld_lds16(A + (size_t)(m0 + w * 16 + sr) * 1024 + k0 + sc * 8,
                  &As[buf * 2048 + w * 512]);
#pragma unroll
        for (int ei = 0; ei < 2; ++ei) {
            const int e = w * 2 + ei;
            gld_lds16(W + (size_t)(n0 + e * 16 + sr) * 1024 + k0 + sc * 8,
                      &Bs[buf * 4096 + e * 512]);
        }
    };

    stage(0, 0);

    for (int it = 0; it < 32; ++it) {
        const int cur = it & 1;
        asm volatile("s_barrier" ::: "memory");
        if (it + 1 < 32) {
            stage((it + 1) * 32, cur ^ 1);
            asm volatile("s_waitcnt vmcnt(3)" ::: "memory");
        } else {
            asm volatile("s_waitcnt vmcnt(0)" ::: "memory");
        }
        asm volatile("s_barrier" ::: "memory");

        bf16x8 af[2], bfr[4];
#pragma unroll
        for (int t = 0; t < 2; ++t)
            af[t] = *(const bf16x8*)&As[cur * 2048 + (wm + t * 16 + ml) * 32 + quad * 8];
#pragma unroll
        for (int t = 0; t < 4; ++t)
            bfr[t] = *(const bf16x8*)&Bs[cur * 4096 + (wn + t * 16 + ml) * 32 + quad * 8];
#pragma unroll
        for (int mt = 0; mt < 2; ++mt)
#pragma unroll
            for (int nt = 0; nt < 4; ++nt)
                acc[mt][nt] = MFMA16(af[mt], bfr[nt], acc[mt][nt]);
    }

#pragma unroll
    for (int mt = 0; mt < 2; ++mt)
#pragma unroll
        for (int nt = 0; nt < 4; ++nt)
#pragma unroll
            for (int r = 0; r < 4; ++r) {
                const int row = m0 + wm + mt * 16 + quad * 4 + r;
                const int col = n0 + wn + nt * 16 + ml;
                Y[(size_t)row * 1024 + col] = acc[mt][nt][r];
            }
}

// ---------------------------------------------------------------------------
// Flash attention v6 (unchanged from R7): KV-split, single-buffered V,
// exp2-ready scores, double-buffered K with s_barrier + vmcnt.
// ---------------------------------------------------------------------------
__global__ __launch_bounds__(256, 4) void attn_mfma(const bf16* __restrict__ QKb,
                                                    const bf16* __restrict__ VtT,
                                                    bf16* __restrict__ Pbuf,
                                                    float* __restrict__ Lbuf) {
    const int bid  = blockIdx.x;
    const int hb   = bid & 31;
    const int s    = 79 - (bid >> 5);     // slot, heavy (high qt) first
    int qt, chunk;
    if (s < 8)       { qt = s;                   chunk = 0; }
    else if (s < 24) { qt = 8  + ((s - 8) >> 1); chunk = (s - 8) & 1; }
    else if (s < 48) { qt = 16 + (s - 24) / 3;   chunk = (s - 24) % 3; }
    else             { qt = 24 + ((s - 48) >> 2); chunk = (s - 48) & 3; }
    const int h = hb >> 1, b = hb & 1;

    const int tid  = threadIdx.x;
    const int lane = tid & 63;
    const int w    = tid >> 6;
    const int ml   = lane & 15;
    const int quad = lane >> 4;

    __shared__ __align__(16) bf16 Ks[2][4096];
    __shared__ __align__(16) bf16 Vs[4096];
    __shared__ __align__(16) bf16 Ps[4][16 * 72];

    const bf16* Qbase = QKb + (size_t)b * T_ * 2048 + (size_t)h * HD_;
    const bf16* Kbase = Qbase + 1024;
    const bf16* Vbase = VtT + (size_t)h * HD_ * 4096 + (size_t)b * T_;

    const int qrow = qt * 64 + w * 16 + ml;
    bf16x8 qf[2];
#pragma unroll
    for (int ks = 0; ks < 2; ++ks)
        qf[ks] = *(const bf16x8*)(Qbase + (size_t)qrow * 2048 + ks * 32 + quad * 8);

    f32x4 o_acc[4] = {};
    f32x4 l_acc = {};
    bf16x8 onesf;
#pragma unroll
    for (int j = 0; j < 8; ++j) onesf[j] = (bf16)1.0f;

    const int sr = lane >> 2, sc = lane & 3;
    bf16* ps = &Ps[w][0];

    const int ktbase  = chunk * 8;
    const int nrounds = min(8, qt + 1 - ktbase);

    auto stageK = [&](int ktg, int buf) {
        const int k0 = ktg * 64;
#pragma unroll
        for (int ei = 0; ei < 2; ++ei) {
            const int e = w * 2 + ei;
            const int r = (e & 3) * 16 + sr;
            const int ch = (e >> 2) * 32 + sc * 8;
            gld_lds16(Kbase + (size_t)(k0 + r) * 2048 + ch, &Ks[buf][e * 512]);
        }
    };
    auto stageV = [&](int ktg) {
        const int k0 = ktg * 64;
#pragma unroll
        for (int ei = 0; ei < 2; ++ei) {
            const int e = w * 2 + ei;
            const int r = (e & 3) * 16 + sr;
            const int ch = (e >> 2) * 32 + sc * 8;
            gld_lds16(Vbase + (size_t)r * 4096 + k0 + ch, &Vs[e * 512]);
        }
    };

    auto phase1 = [&](int cur, int ktg) {
        const int k0 = ktg * 64;
#pragma unroll
        for (int nt = 0; nt < 4; ++nt) {
            f32x4 sacc = {};
#pragma unroll
            for (int ks = 0; ks < 2; ++ks) {
                bf16x8 kf = *(const bf16x8*)&Ks[cur][ks * 2048 + (nt * 16 + ml) * 32 + quad * 8];
                sacc = MFMA16(qf[ks], kf, sacc);
            }
            const int kg = k0 + nt * 16 + ml;
#pragma unroll
            for (int r = 0; r < 4; ++r) {
                float arg = sacc[r];
                if (ktg == qt) {
                    const int qg = qt * 64 + w * 16 + quad * 4 + r;
                    if (kg > qg) arg = -1e30f;
                }
                ps[(quad * 4 + r) * 72 + nt * 16 + ml] = (bf16)exp2f(arg);
            }
        }
    };

    auto phase2 = [&]() {
#pragma unroll
        for (int ks = 0; ks < 2; ++ks) {
            bf16x8 pf = *(const bf16x8*)&ps[ml * 72 + ks * 32 + quad * 8];
            l_acc = MFMA16(pf, onesf, l_acc);
#pragma unroll
            for (int nt = 0; nt < 4; ++nt) {
                bf16x8 vf = *(const bf16x8*)&Vs[ks * 2048 + (nt * 16 + ml) * 32 + quad * 8];
                o_acc[nt] = MFMA16(pf, vf, o_acc[nt]);
            }
        }
    };

    stageK(ktbase, 0);

    for (int j = 0; j < nrounds; ++j) {
        const int cur = j & 1;
        const int ktg = ktbase + j;

        asm volatile("s_barrier" ::: "memory");
        stageV(ktg);
        if (j + 1 < nrounds) {
            stageK(ktg + 1, cur ^ 1);
            asm volatile("s_waitcnt vmcnt(4)" ::: "memory");
            asm volatile("s_barrier" ::: "memory");
            phase1(cur, ktg);
            asm volatile("s_waitcnt vmcnt(2)" ::: "memory");
            asm volatile("s_barrier" ::: "memory");
            phase2();
        } else {
            asm volatile("s_waitcnt vmcnt(2)" ::: "memory");
            asm volatile("s_barrier" ::: "memory");
            phase1(cur, ktg);
            asm volatile("s_waitcnt vmcnt(0)" ::: "memory");
            asm volatile("s_barrier" ::: "memory");
            phase2();
        }
    }

    const int slotIdx = hb * 80 + s;
    bf16* pb = Pbuf + (size_t)slotIdx * 4096;
#pragma unroll
    for (int r = 0; r < 4; ++r) {
        const int prow = w * 16 + quad * 4 + r;
#pragma unroll
        for (int nt = 0; nt < 4; ++nt)
            pb[prow * 64 + nt * 16 + ml] = (bf16)o_acc[nt][r];
        if (ml == 0)
            Lbuf[slotIdx * 64 + prow] = l_acc[r];
    }
}

// ---------------------------------------------------------------------------
// Merge partials: grid 1024 = (qt, h, b); sum <=4 chunks, normalize, write Ab.
// ---------------------------------------------------------------------------
__global__ __launch_bounds__(256) void attn_merge(const bf16* __restrict__ Pbuf,
                                                  const float* __restrict__ Lbuf,
                                                  bf16* __restrict__ Ab) {
    const int gid = blockIdx.x;
    const int qt  = gid >> 5;
    const int hb  = gid & 31;
    const int h = hb >> 1, b = hb & 1;
    int s0;
    if (qt < 8)       s0 = qt;
    else if (qt < 16) s0 = 8 + (qt - 8) * 2;
    else if (qt < 24) s0 = 24 + (qt - 16) * 3;
    else              s0 = 48 + (qt - 24) * 4;
    const int nch = (qt + 8) >> 3;

    const int tid = threadIdx.x;
    const int row = tid >> 2;
    const int cg  = (tid & 3) * 16;

    float acc[16] = {};
    float lsum = 0.f;
    for (int c = 0; c < nch; ++c) {
        const int slotIdx = hb * 80 + s0 + c;
        lsum += Lbuf[slotIdx * 64 + row];
        const bf16* pb = Pbuf + (size_t)slotIdx * 4096 + row * 64 + cg;
        bf16x8 v0 = *(const bf16x8*)pb;
        bf16x8 v1 = *(const bf16x8*)(pb + 8);
#pragma unroll
        for (int j = 0; j < 8; ++j) { acc[j] += (float)v0[j]; acc[8 + j] += (float)v1[j]; }
    }
    const float rcl = 1.0f / lsum;
    bf16x8 o0, o1;
#pragma unroll
    for (int j = 0; j < 8; ++j) { o0[j] = (bf16)(acc[j] * rcl); o1[j] = (bf16)(acc[8 + j] * rcl); }
    bf16* dst = Ab + (size_t)(b * T_ + qt * 64 + row) * 1024 + h * 64 + cg;
    *(bf16x8*)dst = o0;
    *(bf16x8*)(dst + 8) = o1;
}

// ---------------------------------------------------------------------------
extern "C" void kernel_launch(void* const* d_in, const int* in_sizes, int n_in,
                              void* d_out, int out_size, void* d_ws, size_t ws_size,
                              hipStream_t stream) {
    const float* x  = (const float*)d_in[0];
    const float* Wq = (const float*)d_in[1];
    const float* Wk = (const float*)d_in[2];
    const float* Wv = (const float*)d_in[3];
    const float* Wo = (const float*)d_in[4];
    float* out = (float*)d_out;

    const size_t n_x = (size_t)B_ * T_ * C_;  // 4 Mi
    const size_t n_w = (size_t)C_ * C_;       // 1 Mi

    bf16* xb   = (bf16*)d_ws;        // 8 MB
    bf16* Wqk  = xb + n_x;           // 4 MB ([Wq; Wk])
    bf16* Wvb  = Wqk + 2 * n_w;      // 2 MB
    bf16* Wob  = Wvb + n_w;          // 2 MB
    bf16* QKb  = Wob + n_w;          // 16 MB (4096 x 2048)
    bf16* VtT  = QKb + 2 * n_x;      // 8 MB (1024 x 4096)
    bf16* Ab   = VtT + n_x;          // 8 MB (4096 x 1024)
    bf16* Pbuf = Ab + n_x;           // 21 MB (2560 x 64 x 64)
    float* Lbuf = (float*)(Pbuf + (size_t)2560 * 4096);  // 0.66 MB

    cast_all<<<5120, 256, 0, stream>>>(x, Wq, Wk, Wv, Wo, xb, Wqk, Wvb, Wob);

    proj_fused<<<768, 256, 0, stream>>>(xb, Wqk, Wvb, QKb, VtT);

    attn_mfma<<<2560, 256, 0, stream>>>(QKb, VtT, Pbuf, Lbuf);
    attn_merge<<<1024, 256, 0, stream>>>(Pbuf, Lbuf, Ab);

    gemm_wo<<<dim3(1024 / 128, 4096 / 64), 256, 0, stream>>>(Ab, Wob, out);
}

// Round 9
// 180.478 us; speedup vs baseline: 1.0779x; 1.0779x over previous
//
#include <hip/hip_runtime.h>
#include <hip/hip_bf16.h>
#include <cstdint>
#include <cstddef>
#include <cmath>

#define B_  2
#define T_  2048
#define C_  1024
#define NH_ 16
#define HD_ 64

typedef __bf16 bf16;
typedef bf16  bf16x8 __attribute__((ext_vector_type(8)));
typedef bf16  bf16x4 __attribute__((ext_vector_type(4)));
typedef float f32x4  __attribute__((ext_vector_type(4)));

#define MFMA16(a, b, c) __builtin_amdgcn_mfma_f32_16x16x32_bf16((a), (b), (c), 0, 0, 0)

// Async 16B global->LDS; LDS dest = wave-uniform base + lane*16.
__device__ __forceinline__ void gld_lds16(const bf16* g, bf16* lds_base_uniform) {
    __builtin_amdgcn_global_load_lds(
        (const __attribute__((address_space(1))) uint32_t*)g,
        (__attribute__((address_space(3))) uint32_t*)lds_base_uniform,
        16, 0, 0);
}

// ---------------------------------------------------------------------------
// Fused casts: blocks 0..4095 -> x (4 Mi elems); 4096..5119 -> all 4 weights.
// Wq is pre-scaled by 0.125*log2(e) so attention scores are exp2-ready.
// ---------------------------------------------------------------------------
__global__ __launch_bounds__(256) void cast_all(const float* __restrict__ x,
                                                const float* __restrict__ Wq,
                                                const float* __restrict__ Wk,
                                                const float* __restrict__ Wv,
                                                const float* __restrict__ Wo,
                                                bf16* __restrict__ xb,
                                                bf16* __restrict__ Wqk,
                                                bf16* __restrict__ Wvb,
                                                bf16* __restrict__ Wob) {
    const int bid = blockIdx.x;
    if (bid < 4096) {
        const int i = bid * 256 + threadIdx.x;
        float4 v = ((const float4*)x)[i];
        ((bf16x4*)xb)[i] = bf16x4{ (bf16)v.x, (bf16)v.y, (bf16)v.z, (bf16)v.w };
    } else {
        const float C1 = 0.1803368801111f;   // 0.125 * log2(e)
        const int i = (bid - 4096) * 256 + threadIdx.x;
        const int nw4 = C_ * C_ / 4;
        float4 q = ((const float4*)Wq)[i];
        float4 k = ((const float4*)Wk)[i];
        float4 v = ((const float4*)Wv)[i];
        float4 o = ((const float4*)Wo)[i];
        ((bf16x4*)Wqk)[i]       = bf16x4{ (bf16)(q.x * C1), (bf16)(q.y * C1),
                                          (bf16)(q.z * C1), (bf16)(q.w * C1) };
        ((bf16x4*)Wqk)[nw4 + i] = bf16x4{ (bf16)k.x, (bf16)k.y, (bf16)k.z, (bf16)k.w };
        ((bf16x4*)Wvb)[i]       = bf16x4{ (bf16)v.x, (bf16)v.y, (bf16)v.z, (bf16)v.w };
        ((bf16x4*)Wob)[i]       = bf16x4{ (bf16)o.x, (bf16)o.y, (bf16)o.z, (bf16)o.w };
    }
}

// ---------------------------------------------------------------------------
// 128x128 GEMM tile device fn (NT), R7 single-buffer structure.
// ---------------------------------------------------------------------------
__device__ __forceinline__ void gemm_tile(bf16* As, bf16* Bs,
                                          const bf16* __restrict__ A,
                                          const bf16* __restrict__ W,
                                          bf16* __restrict__ Y,
                                          int N, int K, int m0, int n0) {
    const int tid  = threadIdx.x;
    const int lane = tid & 63;
    const int w    = tid >> 6;
    const int ml   = lane & 15;
    const int quad = lane >> 4;
    const int wm   = (w >> 1) * 64;
    const int wn   = (w & 1) * 64;
    const int sr   = lane >> 2;
    const int sc   = lane & 3;

    f32x4 acc[4][4] = {};

    for (int k0 = 0; k0 < K; k0 += 32) {
        __syncthreads();
#pragma unroll
        for (int ei = 0; ei < 2; ++ei) {
            const int e = w * 2 + ei;
            gld_lds16(A + (size_t)(m0 + e * 16 + sr) * K + k0 + sc * 8, &As[e * 512]);
            gld_lds16(W + (size_t)(n0 + e * 16 + sr) * K + k0 + sc * 8, &Bs[e * 512]);
        }
        __builtin_amdgcn_s_waitcnt(0);
        __syncthreads();

        bf16x8 af[4], bfr[4];
#pragma unroll
        for (int t = 0; t < 4; ++t) {
            af[t]  = *(const bf16x8*)&As[(wm + t * 16 + ml) * 32 + quad * 8];
            bfr[t] = *(const bf16x8*)&Bs[(wn + t * 16 + ml) * 32 + quad * 8];
        }
#pragma unroll
        for (int mt = 0; mt < 4; ++mt)
#pragma unroll
            for (int nt = 0; nt < 4; ++nt)
                acc[mt][nt] = MFMA16(af[mt], bfr[nt], acc[mt][nt]);
    }

#pragma unroll
    for (int mt = 0; mt < 4; ++mt)
#pragma unroll
        for (int nt = 0; nt < 4; ++nt)
#pragma unroll
            for (int r = 0; r < 4; ++r) {
                const int row = m0 + wm + mt * 16 + quad * 4 + r;
                const int col = n0 + wn + nt * 16 + ml;
                Y[(size_t)row * N + col] = (bf16)acc[mt][nt][r];
            }
}

// Fused projections: blocks 0..511 -> QK = x @ Wqk^T   [4096 x 2048]
//                    blocks 512..767 -> V^T = Wv @ x^T [1024 x 4096]
__global__ __launch_bounds__(256) void proj_fused(const bf16* __restrict__ xb,
                                                  const bf16* __restrict__ Wqk,
                                                  const bf16* __restrict__ Wvb,
                                                  bf16* __restrict__ QKb,
                                                  bf16* __restrict__ VtT) {
    __shared__ __align__(16) bf16 As[128 * 32];
    __shared__ __align__(16) bf16 Bs[128 * 32];
    const int bid = blockIdx.x;
    if (bid < 512) {
        gemm_tile(As, Bs, xb, Wqk, QKb, 2048, 1024, (bid >> 4) * 128, (bid & 15) * 128);
    } else {
        const int b2 = bid - 512;
        gemm_tile(As, Bs, Wvb, xb, VtT, 4096, 1024, (b2 >> 5) * 128, (b2 & 31) * 128);
    }
}

// ---------------------------------------------------------------------------
// Output GEMM: out[4096,1024] = Ab @ Wo^T, fp32 out. 64x128 tile -> 512 blocks.
// R7 single-buffer structure.
// ---------------------------------------------------------------------------
__global__ __launch_bounds__(256) void gemm_wo(const bf16* __restrict__ A,
                                               const bf16* __restrict__ W,
                                               float* __restrict__ Y) {
    __shared__ __align__(16) bf16 As[64 * 32];
    __shared__ __align__(16) bf16 Bs[128 * 32];
    const int tid  = threadIdx.x;
    const int lane = tid & 63;
    const int w    = tid >> 6;
    const int ml   = lane & 15;
    const int quad = lane >> 4;
    const int wm   = (w >> 1) * 32;
    const int wn   = (w & 1) * 64;
    const int m0   = blockIdx.y * 64;
    const int n0   = blockIdx.x * 128;
    const int sr   = lane >> 2;
    const int sc   = lane & 3;

    f32x4 acc[2][4] = {};

    for (int k0 = 0; k0 < 1024; k0 += 32) {
        __syncthreads();
        gld_lds16(A + (size_t)(m0 + w * 16 + sr) * 1024 + k0 + sc * 8, &As[w * 512]);
#pragma unroll
        for (int ei = 0; ei < 2; ++ei) {
            const int e = w * 2 + ei;
            gld_lds16(W + (size_t)(n0 + e * 16 + sr) * 1024 + k0 + sc * 8, &Bs[e * 512]);
        }
        __builtin_amdgcn_s_waitcnt(0);
        __syncthreads();

        bf16x8 af[2], bfr[4];
#pragma unroll
        for (int t = 0; t < 2; ++t)
            af[t] = *(const bf16x8*)&As[(wm + t * 16 + ml) * 32 + quad * 8];
#pragma unroll
        for (int t = 0; t < 4; ++t)
            bfr[t] = *(const bf16x8*)&Bs[(wn + t * 16 + ml) * 32 + quad * 8];
#pragma unroll
        for (int mt = 0; mt < 2; ++mt)
#pragma unroll
            for (int nt = 0; nt < 4; ++nt)
                acc[mt][nt] = MFMA16(af[mt], bfr[nt], acc[mt][nt]);
    }

#pragma unroll
    for (int mt = 0; mt < 2; ++mt)
#pragma unroll
        for (int nt = 0; nt < 4; ++nt)
#pragma unroll
            for (int r = 0; r < 4; ++r) {
                const int row = m0 + wm + mt * 16 + quad * 4 + r;
                const int col = n0 + wn + nt * 16 + ml;
                Y[(size_t)row * 1024 + col] = acc[mt][nt][r];
            }
}

// ---------------------------------------------------------------------------
// Flash attention v7: as v6 (KV-split, single-buffered V, exp2-ready scores)
// + raw v_exp_f32 via __builtin_amdgcn_exp2f + truncation bf16 stores for P
// (bits>>16; bias cancels in O/L since the same P feeds both).
// ---------------------------------------------------------------------------
__global__ __launch_bounds__(256, 4) void attn_mfma(const bf16* __restrict__ QKb,
                                                    const bf16* __restrict__ VtT,
                                                    bf16* __restrict__ Pbuf,
                                                    float* __restrict__ Lbuf) {
    const int bid  = blockIdx.x;
    const int hb   = bid & 31;
    const int s    = 79 - (bid >> 5);     // slot, heavy (high qt) first
    int qt, chunk;
    if (s < 8)       { qt = s;                   chunk = 0; }
    else if (s < 24) { qt = 8  + ((s - 8) >> 1); chunk = (s - 8) & 1; }
    else if (s < 48) { qt = 16 + (s - 24) / 3;   chunk = (s - 24) % 3; }
    else             { qt = 24 + ((s - 48) >> 2); chunk = (s - 48) & 3; }
    const int h = hb >> 1, b = hb & 1;

    const int tid  = threadIdx.x;
    const int lane = tid & 63;
    const int w    = tid >> 6;
    const int ml   = lane & 15;
    const int quad = lane >> 4;

    __shared__ __align__(16) bf16 Ks[2][4096];
    __shared__ __align__(16) bf16 Vs[4096];
    __shared__ __align__(16) bf16 Ps[4][16 * 72];

    const bf16* Qbase = QKb + (size_t)b * T_ * 2048 + (size_t)h * HD_;
    const bf16* Kbase = Qbase + 1024;
    const bf16* Vbase = VtT + (size_t)h * HD_ * 4096 + (size_t)b * T_;

    const int qrow = qt * 64 + w * 16 + ml;
    bf16x8 qf[2];
#pragma unroll
    for (int ks = 0; ks < 2; ++ks)
        qf[ks] = *(const bf16x8*)(Qbase + (size_t)qrow * 2048 + ks * 32 + quad * 8);

    f32x4 o_acc[4] = {};
    f32x4 l_acc = {};
    bf16x8 onesf;
#pragma unroll
    for (int j = 0; j < 8; ++j) onesf[j] = (bf16)1.0f;

    const int sr = lane >> 2, sc = lane & 3;
    bf16* ps = &Ps[w][0];
    uint16_t* ps16 = (uint16_t*)ps;

    const int ktbase  = chunk * 8;
    const int nrounds = min(8, qt + 1 - ktbase);

    auto stageK = [&](int ktg, int buf) {
        const int k0 = ktg * 64;
#pragma unroll
        for (int ei = 0; ei < 2; ++ei) {
            const int e = w * 2 + ei;
            const int r = (e & 3) * 16 + sr;
            const int ch = (e >> 2) * 32 + sc * 8;
            gld_lds16(Kbase + (size_t)(k0 + r) * 2048 + ch, &Ks[buf][e * 512]);
        }
    };
    auto stageV = [&](int ktg) {
        const int k0 = ktg * 64;
#pragma unroll
        for (int ei = 0; ei < 2; ++ei) {
            const int e = w * 2 + ei;
            const int r = (e & 3) * 16 + sr;
            const int ch = (e >> 2) * 32 + sc * 8;
            gld_lds16(Vbase + (size_t)r * 4096 + k0 + ch, &Vs[e * 512]);
        }
    };

    auto phase1 = [&](int cur, int ktg) {
        const int k0 = ktg * 64;
#pragma unroll
        for (int nt = 0; nt < 4; ++nt) {
            f32x4 sacc = {};
#pragma unroll
            for (int ks = 0; ks < 2; ++ks) {
                bf16x8 kf = *(const bf16x8*)&Ks[cur][ks * 2048 + (nt * 16 + ml) * 32 + quad * 8];
                sacc = MFMA16(qf[ks], kf, sacc);
            }
            const int kg = k0 + nt * 16 + ml;
#pragma unroll
            for (int r = 0; r < 4; ++r) {
                float arg = sacc[r];
                if (ktg == qt) {
                    const int qg = qt * 64 + w * 16 + quad * 4 + r;
                    if (kg > qg) arg = -1e30f;
                }
                const float p = __builtin_amdgcn_exp2f(arg);
                ps16[(quad * 4 + r) * 72 + nt * 16 + ml] =
                    (uint16_t)(__builtin_bit_cast(uint32_t, p) >> 16);
            }
        }
    };

    auto phase2 = [&]() {
#pragma unroll
        for (int ks = 0; ks < 2; ++ks) {
            bf16x8 pf = *(const bf16x8*)&ps[ml * 72 + ks * 32 + quad * 8];
            l_acc = MFMA16(pf, onesf, l_acc);
#pragma unroll
            for (int nt = 0; nt < 4; ++nt) {
                bf16x8 vf = *(const bf16x8*)&Vs[ks * 2048 + (nt * 16 + ml) * 32 + quad * 8];
                o_acc[nt] = MFMA16(pf, vf, o_acc[nt]);
            }
        }
    };

    stageK(ktbase, 0);

    for (int j = 0; j < nrounds; ++j) {
        const int cur = j & 1;
        const int ktg = ktbase + j;

        asm volatile("s_barrier" ::: "memory");
        stageV(ktg);
        if (j + 1 < nrounds) {
            stageK(ktg + 1, cur ^ 1);
            asm volatile("s_waitcnt vmcnt(4)" ::: "memory");
            asm volatile("s_barrier" ::: "memory");
            phase1(cur, ktg);
            asm volatile("s_waitcnt vmcnt(2)" ::: "memory");
            asm volatile("s_barrier" ::: "memory");
            phase2();
        } else {
            asm volatile("s_waitcnt vmcnt(2)" ::: "memory");
            asm volatile("s_barrier" ::: "memory");
            phase1(cur, ktg);
            asm volatile("s_waitcnt vmcnt(0)" ::: "memory");
            asm volatile("s_barrier" ::: "memory");
            phase2();
        }
    }

    const int slotIdx = hb * 80 + s;
    bf16* pb = Pbuf + (size_t)slotIdx * 4096;
#pragma unroll
    for (int r = 0; r < 4; ++r) {
        const int prow = w * 16 + quad * 4 + r;
#pragma unroll
        for (int nt = 0; nt < 4; ++nt)
            pb[prow * 64 + nt * 16 + ml] = (bf16)o_acc[nt][r];
        if (ml == 0)
            Lbuf[slotIdx * 64 + prow] = l_acc[r];
    }
}

// ---------------------------------------------------------------------------
// Merge partials: grid 1024 = (qt, h, b); sum <=4 chunks, normalize, write Ab.
// ---------------------------------------------------------------------------
__global__ __launch_bounds__(256) void attn_merge(const bf16* __restrict__ Pbuf,
                                                  const float* __restrict__ Lbuf,
                                                  bf16* __restrict__ Ab) {
    const int gid = blockIdx.x;
    const int qt  = gid >> 5;
    const int hb  = gid & 31;
    const int h = hb >> 1, b = hb & 1;
    int s0;
    if (qt < 8)       s0 = qt;
    else if (qt < 16) s0 = 8 + (qt - 8) * 2;
    else if (qt < 24) s0 = 24 + (qt - 16) * 3;
    else              s0 = 48 + (qt - 24) * 4;
    const int nch = (qt + 8) >> 3;

    const int tid = threadIdx.x;
    const int row = tid >> 2;
    const int cg  = (tid & 3) * 16;

    float acc[16] = {};
    float lsum = 0.f;
    for (int c = 0; c < nch; ++c) {
        const int slotIdx = hb * 80 + s0 + c;
        lsum += Lbuf[slotIdx * 64 + row];
        const bf16* pb = Pbuf + (size_t)slotIdx * 4096 + row * 64 + cg;
        bf16x8 v0 = *(const bf16x8*)pb;
        bf16x8 v1 = *(const bf16x8*)(pb + 8);
#pragma unroll
        for (int j = 0; j < 8; ++j) { acc[j] += (float)v0[j]; acc[8 + j] += (float)v1[j]; }
    }
    const float rcl = 1.0f / lsum;
    bf16x8 o0, o1;
#pragma unroll
    for (int j = 0; j < 8; ++j) { o0[j] = (bf16)(acc[j] * rcl); o1[j] = (bf16)(acc[8 + j] * rcl); }
    bf16* dst = Ab + (size_t)(b * T_ + qt * 64 + row) * 1024 + h * 64 + cg;
    *(bf16x8*)dst = o0;
    *(bf16x8*)(dst + 8) = o1;
}

// ---------------------------------------------------------------------------
extern "C" void kernel_launch(void* const* d_in, const int* in_sizes, int n_in,
                              void* d_out, int out_size, void* d_ws, size_t ws_size,
                              hipStream_t stream) {
    const float* x  = (const float*)d_in[0];
    const float* Wq = (const float*)d_in[1];
    const float* Wk = (const float*)d_in[2];
    const float* Wv = (const float*)d_in[3];
    const float* Wo = (const float*)d_in[4];
    float* out = (float*)d_out;

    const size_t n_x = (size_t)B_ * T_ * C_;  // 4 Mi
    const size_t n_w = (size_t)C_ * C_;       // 1 Mi

    bf16* xb   = (bf16*)d_ws;        // 8 MB
    bf16* Wqk  = xb + n_x;           // 4 MB ([Wq; Wk])
    bf16* Wvb  = Wqk + 2 * n_w;      // 2 MB
    bf16* Wob  = Wvb + n_w;          // 2 MB
    bf16* QKb  = Wob + n_w;          // 16 MB (4096 x 2048)
    bf16* VtT  = QKb + 2 * n_x;      // 8 MB (1024 x 4096)
    bf16* Ab   = VtT + n_x;          // 8 MB (4096 x 1024)
    bf16* Pbuf = Ab + n_x;           // 21 MB (2560 x 64 x 64)
    float* Lbuf = (float*)(Pbuf + (size_t)2560 * 4096);  // 0.66 MB

    cast_all<<<5120, 256, 0, stream>>>(x, Wq, Wk, Wv, Wo, xb, Wqk, Wvb, Wob);

    proj_fused<<<768, 256, 0, stream>>>(xb, Wqk, Wvb, QKb, VtT);

    attn_mfma<<<2560, 256, 0, stream>>>(QKb, VtT, Pbuf, Lbuf);
    attn_merge<<<1024, 256, 0, stream>>>(Pbuf, Lbuf, Ab);

    gemm_wo<<<dim3(1024 / 128, 4096 / 64), 256, 0, stream>>>(Ab, Wob, out);
}